// Round 9
// baseline (1481.813 us; speedup 1.0000x reference)
//
#include <hip/hip_runtime.h>
#include <cstdint>
#include <cstddef>

// ---------------- problem geometry ----------------
#define H_DIM   2560
#define DINNER  8192
#define GHEADS  32
#define DGATE   4096
#define DH      128
#define BSZ     2
#define LSEQ    4096
#define MROWS   (BSZ*LSEQ)     // 8192 token rows
#define NXPAD   4352           // xzx width: 4096 x | 32 B | 32 C | 192 pad (=17*256)
#define NWCOMB  8448           // fused B rows: [x|B|C|pad] 4352 + z 4096 (=33*256)
#define NCHUNK  64
#define SCHUNK  (LSEQ/NCHUNK)  // 64

typedef __attribute__((ext_vector_type(4))) float    f32x4;
typedef __attribute__((ext_vector_type(8))) _Float16 f16x8;
typedef unsigned short u16;
typedef unsigned int   u32;

static __device__ __forceinline__ u16 f2h(float f) {
  _Float16 h = (_Float16)f;          // v_cvt_f16_f32, RNE
  union { _Float16 h; u16 u; } v; v.h = h; return v.u;
}
static __device__ __forceinline__ float h2f(u16 u) {
  union { u16 u; _Float16 h; } v; v.u = u; return (float)v.h;
}
static __device__ __forceinline__ float silu(float x) {
  return x / (1.0f + expf(-x));
}

// ---------------- prep casts (f32 -> fp16) ----------------
__global__ void cast_f32_f16(const float* __restrict__ in, u16* __restrict__ out, int n4) {
  int i = blockIdx.x * blockDim.x + threadIdx.x;
  if (i < n4) {
    f32x4 v = ((const f32x4*)in)[i];
    u32 p0 = (u32)f2h(v[0]) | ((u32)f2h(v[1]) << 16);
    u32 p1 = (u32)f2h(v[2]) | ((u32)f2h(v[3]) << 16);
    ((uint2*)out)[i] = make_uint2(p0, p1);
  }
}

// wcomb rows (8448): 0..4095 = Wqkv x-rows, 4096..4127 = Wb, 4128..4159 = Wa,
//                    4160..4351 = 0, 4352..8447 = Wqkv z-rows (4096..8191)
__global__ void build_wc(const float* __restrict__ Wqkv, const float* __restrict__ Wb,
                         const float* __restrict__ Wa, u16* __restrict__ wcomb) {
  int row = blockIdx.x;              // 0..8447
  const float* src = nullptr;
  if (row < 4096)              src = Wqkv + (size_t)row * H_DIM;
  else if (row < 4128)         src = Wb + (size_t)(row - 4096) * H_DIM;
  else if (row < 4160)         src = Wa + (size_t)(row - 4128) * H_DIM;
  else if (row >= NXPAD)       src = Wqkv + (size_t)(4096 + row - NXPAD) * H_DIM;
  u16* oh = wcomb + (size_t)row * H_DIM;
  for (int i = threadIdx.x; i < H_DIM / 4; i += blockDim.x) {
    u32 p0 = 0, p1 = 0;
    if (src) {
      f32x4 v = ((const f32x4*)src)[i];
      p0 = (u32)f2h(v[0]) | ((u32)f2h(v[1]) << 16);
      p1 = (u32)f2h(v[2]) | ((u32)f2h(v[3]) << 16);
    }
    ((uint2*)oh)[i] = make_uint2(p0, p1);
  }
}

// ---------------- GEMM: 128x256 tile, 3-buffer depth-2 pipeline ----------------
static __device__ __forceinline__ void gload16(const u16* g, u16* l) {
  __builtin_amdgcn_global_load_lds(
      (const __attribute__((address_space(1))) u32*)g,
      (__attribute__((address_space(3))) u32*)l, 16, 0, 0);
}

#define BAR()    asm volatile("s_barrier" ::: "memory")
#define WAITV6() asm volatile("s_waitcnt vmcnt(6)" ::: "memory")
#define WAITV3() asm volatile("s_waitcnt vmcnt(3)" ::: "memory")
#define WAITV0() asm volatile("s_waitcnt vmcnt(0)" ::: "memory")

// C[m,n] = sum_k A[m,k]*Bt[n,k], fp16 in. 128M x 256N tile, 512 thr (8 waves
// 2x4, per-wave 64x64, 4x4 16x16x32 frags). THREE LDS buffers (72 KB total,
// 2 blocks/CU): a buffer's 3 staging loads are issued ~2 compute phases before
// their counted-vmcnt wait -> covers HBM-class latency; vmcnt never drains to
// 0 in the main loop (T4). LDS XOR swizzle (T2, both-sides): 16B slot ^=
// (row>>1)&3 via pre-swizzled global source col + same XOR on fragment reads
// (bank-conflict 0, verified r7). setprio around MFMA (T5).
// Column-major XCD swizzle (B-stationary): bx = lsw>>6, by = lsw&63 -> each
// XCD iterates by within a bx column; B panel (1.3 MB) stays L2-resident.
// Output routing: bx < nf32 -> f32 at col bx*256 (ldc32); else -> f16 at
// col (bx-nf32)*256 (ldc16).  K % 32 == 0, K/32 > 3. M fixed 8192 (64 by-tiles).
__global__ __launch_bounds__(512, 4)
void gemm3(const u16* __restrict__ A, const u16* __restrict__ Bt,
           float* __restrict__ Cf32, u16* __restrict__ Cf16,
           int K, int ldc32, int ldc16, int nbx, int nf32) {
  __shared__ __align__(16) u16 As0[128 * 32];
  __shared__ __align__(16) u16 As1[128 * 32];
  __shared__ __align__(16) u16 As2[128 * 32];
  __shared__ __align__(16) u16 Bs0[256 * 32];
  __shared__ __align__(16) u16 Bs1[256 * 32];
  __shared__ __align__(16) u16 Bs2[256 * 32];
  const int tid  = threadIdx.x;
  const int lane = tid & 63;
  const int wave = tid >> 6;          // 0..7
  const int wm = (wave & 1) * 64;
  const int wn = (wave >> 1) * 64;
  const int bid = blockIdx.x;
  const int cpx = nbx << 3;           // grid/8 = nbx*64/8
  const int lsw = (bid & 7) * cpx + (bid >> 3);
  const int bx  = lsw >> 6;           // column-major: B-panel stationary per XCD
  const int by  = lsw & 63;
  const size_t bm = (size_t)by * 128;
  const u16* Ab = A  + bm * (size_t)K;
  const u16* Bb = Bt + (size_t)bx * 256 * K;

  // staging: thread covers linear LDS slot tid*16B; row = tid>>2, dest c8 =
  // tid&3; SOURCE col pre-swizzled: c8 ^ ((row>>1)&3). (B second half row+128
  // has the same mask.)
  const int srow = tid >> 2;                                  // 0..127
  const int scol = (((tid & 3) ^ ((srow >> 1) & 3)) << 3);    // element col

  f32x4 acc[4][4];
#pragma unroll
  for (int i = 0; i < 4; i++)
#pragma unroll
    for (int j = 0; j < 4; j++) acc[i][j] = (f32x4){0.f, 0.f, 0.f, 0.f};

#define STAGE(AS, BS, kk)                                                \
  do {                                                                   \
    gload16(Ab + (size_t)srow * K + (kk) + scol, &AS[tid * 8]);          \
    gload16(Bb + (size_t)srow * K + (kk) + scol, &BS[tid * 8]);          \
    gload16(Bb + (size_t)(128 + srow) * K + (kk) + scol, &BS[4096 + tid * 8]); \
  } while (0)

#define COMPUTE(AS, BS)                                                           \
  do {                                                                            \
    const int fr = lane & 15;                                                     \
    const int fo = (((lane >> 4) ^ ((fr >> 1) & 3)) << 3);  /* swizzled k-off */  \
    f16x8 av[4], bv[4];                                                           \
    _Pragma("unroll")                                                             \
    for (int i = 0; i < 4; i++) av[i] = *(const f16x8*)&AS[(wm + i * 16 + fr) * 32 + fo]; \
    _Pragma("unroll")                                                             \
    for (int j = 0; j < 4; j++) bv[j] = *(const f16x8*)&BS[(wn + j * 16 + fr) * 32 + fo]; \
    __builtin_amdgcn_s_setprio(1);                                                \
    _Pragma("unroll")                                                             \
    for (int i = 0; i < 4; i++)                                                   \
      _Pragma("unroll")                                                           \
      for (int j = 0; j < 4; j++)                                                 \
        acc[i][j] = __builtin_amdgcn_mfma_f32_16x16x32_f16(av[i], bv[j], acc[i][j], 0, 0, 0); \
    __builtin_amdgcn_s_setprio(0);                                                \
  } while (0)

  const int S = K >> 5;               // K/32 steps (>3)
  // prologue: fill 3 buffers (9 loads); retire buf0's (oldest 3)
  STAGE(As0, Bs0, 0);
  STAGE(As1, Bs1, 32);
  STAGE(As2, Bs2, 64);
  WAITV6();
  BAR();
  int i = 0;
  for (; i + 3 < S; i += 3) {
    // step i (buf0); refill buf0 <- step i+3 (always valid: i+3 < S)
    COMPUTE(As0, Bs0); BAR();
    STAGE(As0, Bs0, (i + 3) * 32);
    WAITV6(); BAR();                  // retires buf1(step i+1)'s loads
    // step i+1 (buf1); refill buf1 <- step i+4
    COMPUTE(As1, Bs1); BAR();
    if (i + 4 < S) STAGE(As1, Bs1, (i + 4) * 32);
    WAITV6(); BAR();                  // retires buf2(step i+2)'s loads
    // step i+2 (buf2); refill buf2 <- step i+5
    COMPUTE(As2, Bs2); BAR();
    if (i + 5 < S) STAGE(As2, Bs2, (i + 5) * 32);
    WAITV6(); BAR();                  // retires buf0(step i+3)'s loads
  }
  // tail: r = S - i in {1,2,3}; outstanding <= 6 (buf0/buf1's possibly)
  WAITV3(); BAR();                    // buf0's loads retired across all waves
  COMPUTE(As0, Bs0);
  if (S - i >= 2) { WAITV0(); BAR(); COMPUTE(As1, Bs1); }
  if (S - i >= 3) { COMPUTE(As2, Bs2); }
#undef STAGE
#undef COMPUTE

  // C/D layout: col = lane&15, row = (lane>>4)*4 + reg   [verified m89/m91]
  const int cr = (lane >> 4) * 4, ccol = lane & 15;
  if (bx < nf32) {
    const size_t cb = (size_t)bx * 256;
#pragma unroll
    for (int i2 = 0; i2 < 4; i2++)
#pragma unroll
      for (int j = 0; j < 4; j++)
#pragma unroll
        for (int r = 0; r < 4; r++) {
          size_t row = bm + wm + i2 * 16 + cr + r;
          size_t col = cb + wn + j * 16 + ccol;
          Cf32[row * ldc32 + col] = acc[i2][j][r];
        }
  } else {
    const size_t cb = (size_t)(bx - nf32) * 256;
#pragma unroll
    for (int i2 = 0; i2 < 4; i2++)
#pragma unroll
      for (int j = 0; j < 4; j++)
#pragma unroll
        for (int r = 0; r < 4; r++) {
          size_t row = bm + wm + i2 * 16 + cr + r;
          size_t col = cb + wn + j * 16 + ccol;
          Cf16[row * ldc16 + col] = f2h(acc[i2][j][r]);
        }
  }
}

// ---------------- chunked SSM scan ----------------
// xzx: [M][NXPAD] f32 (x 0..4095 | B 4096..4127 | C 4128..4159 | pad). xzz: [M][4096] fp16.
__global__ __launch_bounds__(64)
void scan_pass1(const float* __restrict__ xzx, const float* __restrict__ conv_w,
                const float* __restrict__ A_log, const float* __restrict__ dt_bias,
                float* __restrict__ E) {
  const int bid = blockIdx.x;
  const int c   = bid & (NCHUNK - 1);
  const int bg  = bid >> 6;
  const int g   = bg & (GHEADS - 1);
  const int b   = bg >> 5;
  const int lane = threadIdx.x;
  const int ch0 = g * DH + lane, ch1 = ch0 + 64;

  const f32x4 w0 = ((const f32x4*)conv_w)[ch0];
  const f32x4 w1 = ((const f32x4*)conv_w)[ch1];
  const float dt = log1pf(expf(dt_bias[g]));
  const float Ac = -expf(A_log[g]);
  const float dA = expf(dt * Ac);

  const int l0 = c * SCHUNK;
  const float* base = xzx + (size_t)b * LSEQ * NXPAD;

  float xm3 = 0, xm2 = 0, xm1 = 0, Xm3 = 0, Xm2 = 0, Xm1 = 0;
#pragma unroll
  for (int j = 0; j < 3; j++) {
    int l = l0 - 3 + j;
    float v0 = 0, v1 = 0;
    if (l >= 0) {
      const float* rp = base + (size_t)l * NXPAD;
      v0 = rp[ch0]; v1 = rp[ch1];
    }
    if (j == 0) { xm3 = v0; Xm3 = v1; }
    else if (j == 1) { xm2 = v0; Xm2 = v1; }
    else { xm1 = v0; Xm1 = v1; }
  }
  float h0 = 0.f, h1 = 0.f;
  for (int t = 0; t < SCHUNK; t++) {
    const float* rp = base + (size_t)(l0 + t) * NXPAD;
    float xc0 = rp[ch0], xc1 = rp[ch1];
    float cx0 = w0[0] * xm3 + w0[1] * xm2 + w0[2] * xm1 + w0[3] * xc0;
    float cx1 = w1[0] * Xm3 + w1[1] * Xm2 + w1[2] * Xm1 + w1[3] * xc1;
    xm3 = xm2; xm2 = xm1; xm1 = xc0;
    Xm3 = Xm2; Xm2 = Xm1; Xm1 = xc1;
    float u = dt * rp[DGATE + g];
    h0 = dA * h0 + u * silu(cx0);
    h1 = dA * h1 + u * silu(cx1);
  }
  float* ep = E + (size_t)bid * DH;
  ep[lane] = h0; ep[lane + 64] = h1;
}

__global__ __launch_bounds__(64)
void scan_pass2(const float* __restrict__ E, float* __restrict__ Hs,
                const float* __restrict__ A_log, const float* __restrict__ dt_bias) {
  const int bg = blockIdx.x;
  const int g = bg & (GHEADS - 1);
  const int lane = threadIdx.x;
  const float dt = log1pf(expf(dt_bias[g]));
  const float Ac = -expf(A_log[g]);
  const float dAS = expf(dt * Ac * (float)SCHUNK);
  float h0 = 0.f, h1 = 0.f;
  for (int c = 0; c < NCHUNK; c++) {
    size_t idx = ((size_t)bg * NCHUNK + c) * DH;
    Hs[idx + lane] = h0; Hs[idx + lane + 64] = h1;
    h0 = dAS * h0 + E[idx + lane];
    h1 = dAS * h1 + E[idx + lane + 64];
  }
}

__global__ __launch_bounds__(64)
void scan_pass3(const float* __restrict__ xzx, const u16* __restrict__ xzz,
                const float* __restrict__ conv_w,
                const float* __restrict__ A_log, const float* __restrict__ dt_bias,
                const float* __restrict__ norm_w, const float* __restrict__ Hs,
                u16* __restrict__ gbuf) {
  const int bid = blockIdx.x;
  const int c   = bid & (NCHUNK - 1);
  const int bg  = bid >> 6;
  const int g   = bg & (GHEADS - 1);
  const int b   = bg >> 5;
  const int lane = threadIdx.x;
  const int ch0 = g * DH + lane, ch1 = ch0 + 64;

  const f32x4 wx0 = ((const f32x4*)conv_w)[ch0];
  const f32x4 wx1 = ((const f32x4*)conv_w)[ch1];
  const f32x4 wz0 = ((const f32x4*)conv_w)[DGATE + ch0];
  const f32x4 wz1 = ((const f32x4*)conv_w)[DGATE + ch1];
  const float nw0 = norm_w[lane], nw1 = norm_w[lane + 64];

  const float dt = log1pf(expf(dt_bias[g]));
  const float Ac = -expf(A_log[g]);
  const float dA = expf(dt * Ac);

  const int l0 = c * SCHUNK;
  const float* basex = xzx + (size_t)b * LSEQ * NXPAD;
  const u16*   basez = xzz + (size_t)b * LSEQ * DGATE;

  float xm3 = 0, xm2 = 0, xm1 = 0, Xm3 = 0, Xm2 = 0, Xm1 = 0;
  float zm3 = 0, zm2 = 0, zm1 = 0, Zm3 = 0, Zm2 = 0, Zm1 = 0;
#pragma unroll
  for (int j = 0; j < 3; j++) {
    int l = l0 - 3 + j;
    float vx0 = 0, vx1 = 0, vz0 = 0, vz1 = 0;
    if (l >= 0) {
      const float* rp = basex + (size_t)l * NXPAD;
      const u16*   rz = basez + (size_t)l * DGATE;
      vx0 = rp[ch0]; vx1 = rp[ch1];
      vz0 = h2f(rz[ch0]); vz1 = h2f(rz[ch1]);
    }
    if (j == 0) { xm3 = vx0; Xm3 = vx1; zm3 = vz0; Zm3 = vz1; }
    else if (j == 1) { xm2 = vx0; Xm2 = vx1; zm2 = vz0; Zm2 = vz1; }
    else { xm1 = vx0; Xm1 = vx1; zm1 = vz0; Zm1 = vz1; }
  }
  float h0 = Hs[(size_t)bid * DH + lane];
  float h1 = Hs[(size_t)bid * DH + lane + 64];
  for (int t = 0; t < SCHUNK; t++) {
    const int l = l0 + t;
    const float* rp = basex + (size_t)l * NXPAD;
    const u16*   rz = basez + (size_t)l * DGATE;
    float xc0 = rp[ch0], xc1 = rp[ch1];
    float zc0 = h2f(rz[ch0]), zc1 = h2f(rz[ch1]);
    float cx0 = wx0[0] * xm3 + wx0[1] * xm2 + wx0[2] * xm1 + wx0[3] * xc0;
    float cx1 = wx1[0] * Xm3 + wx1[1] * Xm2 + wx1[2] * Xm1 + wx1[3] * xc1;
    float cz0 = wz0[0] * zm3 + wz0[1] * zm2 + wz0[2] * zm1 + wz0[3] * zc0;
    float cz1 = wz1[0] * Zm3 + wz1[1] * Zm2 + wz1[2] * Zm1 + wz1[3] * zc1;
    xm3 = xm2; xm2 = xm1; xm1 = xc0;  Xm3 = Xm2; Xm2 = Xm1; Xm1 = xc1;
    zm3 = zm2; zm2 = zm1; zm1 = zc0;  Zm3 = Zm2; Zm2 = Zm1; Zm1 = zc1;
    float bcl = rp[DGATE + g];
    float ccl = rp[DGATE + 32 + g];
    float u = dt * bcl;
    h0 = dA * h0 + u * silu(cx0);
    h1 = dA * h1 + u * silu(cx1);
    float y0 = ccl * h0, y1 = ccl * h1;
    float ss = y0 * y0 + y1 * y1;
    ss += __shfl_xor(ss, 32); ss += __shfl_xor(ss, 16); ss += __shfl_xor(ss, 8);
    ss += __shfl_xor(ss, 4);  ss += __shfl_xor(ss, 2);  ss += __shfl_xor(ss, 1);
    const float sc = rsqrtf(ss * (1.0f / DH) + 1e-6f);
    u16* op = gbuf + (size_t)(b * LSEQ + l) * DGATE + g * DH;
    op[lane]      = f2h(y0 * sc * nw0 * silu(cz0));
    op[lane + 64] = f2h(y1 * sc * nw1 * silu(cz1));
  }
}

// ---------------- launch ----------------
extern "C" void kernel_launch(void* const* d_in, const int* in_sizes, int n_in,
                              void* d_out, int out_size, void* d_ws, size_t ws_size,
                              hipStream_t stream) {
  (void)in_sizes; (void)n_in; (void)out_size; (void)ws_size;
  const float* hs    = (const float*)d_in[0];
  const float* Wqkv  = (const float*)d_in[1];
  const float* Wb    = (const float*)d_in[2];
  const float* Wa    = (const float*)d_in[3];
  const float* convw = (const float*)d_in[4];
  const float* Wout  = (const float*)d_in[5];
  const float* normw = (const float*)d_in[6];
  const float* Alog  = (const float*)d_in[7];
  const float* dtb   = (const float*)d_in[8];
  float* out = (float*)d_out;

  // ws layout (~302 MB; <= 313 proven-safe):
  // [xzx 142.6 | xzz 67.1 | wcomb 43.3 | pad 24 | wout 21.0 | E 2.1 | Hst 2.1]
  char* ws = (char*)d_ws;
  size_t off = 0;
  auto alloc = [&](size_t bytes) { void* p = ws + off; off += (bytes + 255) & ~(size_t)255; return p; };
  float* xzx    = (float*)alloc((size_t)MROWS * NXPAD * 4);      // 142.6 MB
  u16*   xzz    = (u16*)alloc((size_t)MROWS * DGATE * 2);        // 67.1 MB
  u16*   wcomb  = (u16*)alloc((size_t)NWCOMB * H_DIM * 2);       // 43.3 MB
  (void)alloc((size_t)24 << 20);                                 // 24 MB pad (gbuf tail)
  u16*   wout_h = (u16*)alloc((size_t)H_DIM * DGATE * 2);        // 21.0 MB
  float* E      = (float*)alloc((size_t)BSZ * GHEADS * NCHUNK * DH * 4);
  float* Hst    = (float*)alloc((size_t)BSZ * GHEADS * NCHUNK * DH * 4);
  // gbuf (67.1 MB) aliases [wcomb|pad] (67.3 MB): wcomb is dead after GEMM1;
  // pass3 (writer) launches strictly after it. Never touches wout.
  u16*   gbuf   = wcomb;
  // hs_h (fp16, 41.9 MB) lives in d_out (83.9 MB), dead until GEMM2 overwrites it.
  u16*   hs_h   = (u16*)d_out;

  const int n4_hs = MROWS * H_DIM / 4;
  cast_f32_f16<<<(n4_hs + 255) / 256, 256, 0, stream>>>(hs, hs_h, n4_hs);
  build_wc<<<NWCOMB, 256, 0, stream>>>(Wqkv, Wb, Wa, wcomb);
  const int n4_wo = H_DIM * DGATE / 4;
  cast_f32_f16<<<(n4_wo + 255) / 256, 256, 0, stream>>>(Wout, wout_h, n4_wo);

  // Fused GEMM1: [x|B|C -> f32 xzx] + [z -> f16 xzz].  grid 33*64 = 2112
  gemm3<<<33 * 64, 512, 0, stream>>>(hs_h, wcomb, xzx, xzz, H_DIM, NXPAD, DGATE, 33, 17);

  scan_pass1<<<BSZ * GHEADS * NCHUNK, 64, 0, stream>>>(xzx, convw, Alog, dtb, E);
  scan_pass2<<<BSZ * GHEADS, 64, 0, stream>>>(E, Hst, Alog, dtb);
  scan_pass3<<<BSZ * GHEADS * NCHUNK, 64, 0, stream>>>(xzx, xzz, convw, Alog, dtb, normw, Hst, gbuf);

  // GEMM2: out = gated @ W_out^T -> f32 [8192, 2560].  grid 10*64 = 640
  gemm3<<<10 * 64, 512, 0, stream>>>(gbuf, wout_h, out, nullptr, DGATE, H_DIM, 0, 10, 10);
}

// Round 10
// 958.481 us; speedup vs baseline: 1.5460x; 1.5460x over previous
//
#include <hip/hip_runtime.h>
#include <cstdint>
#include <cstddef>

// ---------------- problem geometry ----------------
#define H_DIM   2560
#define DINNER  8192
#define GHEADS  32
#define DGATE   4096
#define DH      128
#define BSZ     2
#define LSEQ    4096
#define MROWS   (BSZ*LSEQ)     // 8192 token rows
#define NXPAD   4352           // xzx width: 4096 x | 32 B | 32 C | 192 pad (=34*128)
#define NWCOMB  8448           // fused B rows: [x|B|C|pad] 4352 + z 4096 (=66*128)
#define NCHUNK  64
#define SCHUNK  (LSEQ/NCHUNK)  // 64

typedef __attribute__((ext_vector_type(4)))  float    f32x4;
typedef __attribute__((ext_vector_type(16))) float    f32x16;
typedef __attribute__((ext_vector_type(8)))  _Float16 f16x8;
typedef unsigned short u16;
typedef unsigned int   u32;

static __device__ __forceinline__ u16 f2h(float f) {
  _Float16 h = (_Float16)f;          // v_cvt_f16_f32, RNE
  union { _Float16 h; u16 u; } v; v.h = h; return v.u;
}
static __device__ __forceinline__ float h2f(u16 u) {
  union { u16 u; _Float16 h; } v; v.u = u; return (float)v.h;
}
static __device__ __forceinline__ float silu(float x) {
  return x / (1.0f + expf(-x));
}

// ---------------- prep casts (f32 -> fp16) ----------------
__global__ void cast_f32_f16(const float* __restrict__ in, u16* __restrict__ out, int n4) {
  int i = blockIdx.x * blockDim.x + threadIdx.x;
  if (i < n4) {
    f32x4 v = ((const f32x4*)in)[i];
    u32 p0 = (u32)f2h(v[0]) | ((u32)f2h(v[1]) << 16);
    u32 p1 = (u32)f2h(v[2]) | ((u32)f2h(v[3]) << 16);
    ((uint2*)out)[i] = make_uint2(p0, p1);
  }
}

// wcomb rows (8448): 0..4095 = Wqkv x-rows, 4096..4127 = Wb, 4128..4159 = Wa,
//                    4160..4351 = 0, 4352..8447 = Wqkv z-rows (4096..8191)
__global__ void build_wc(const float* __restrict__ Wqkv, const float* __restrict__ Wb,
                         const float* __restrict__ Wa, u16* __restrict__ wcomb) {
  int row = blockIdx.x;              // 0..8447
  const float* src = nullptr;
  if (row < 4096)              src = Wqkv + (size_t)row * H_DIM;
  else if (row < 4128)         src = Wb + (size_t)(row - 4096) * H_DIM;
  else if (row < 4160)         src = Wa + (size_t)(row - 4128) * H_DIM;
  else if (row >= NXPAD)       src = Wqkv + (size_t)(4096 + row - NXPAD) * H_DIM;
  u16* oh = wcomb + (size_t)row * H_DIM;
  for (int i = threadIdx.x; i < H_DIM / 4; i += blockDim.x) {
    u32 p0 = 0, p1 = 0;
    if (src) {
      f32x4 v = ((const f32x4*)src)[i];
      p0 = (u32)f2h(v[0]) | ((u32)f2h(v[1]) << 16);
      p1 = (u32)f2h(v[2]) | ((u32)f2h(v[3]) << 16);
    }
    ((uint2*)oh)[i] = make_uint2(p0, p1);
  }
}

// ---------------- GEMM: 128x128 tile, 32x32x16 MFMA, 2-buf counted vmcnt ------
static __device__ __forceinline__ void gload16(const u16* g, u16* l) {
  __builtin_amdgcn_global_load_lds(
      (const __attribute__((address_space(1))) u32*)g,
      (__attribute__((address_space(3))) u32*)l, 16, 0, 0);
}

#define BAR()    asm volatile("s_barrier" ::: "memory")
#define WAITV4() asm volatile("s_waitcnt vmcnt(4)" ::: "memory")
#define WAITV0() asm volatile("s_waitcnt vmcnt(0)" ::: "memory")

// C[m,n] = sum_k A[m,k]*Bt[n,k], fp16 in. 128x128 tile, 256 thr (4 waves 2x2,
// per-wave 64x64 = 2x2 frags of 32x32x16). 32 KB LDS (2-buf) + ~120 VGPR ->
// 4 blocks/CU: cross-block MFMA/stage overlap (m114) is the latency hider.
// Counted vmcnt(4) double-buffer (r7-proven schedule, never drains mid-loop).
// T2 swizzle: 16B slot ^= (row>>1)&3 via pre-swizzled global col + same XOR on
// fragment reads (bank-conflict 0). T5 setprio around MFMA.
// Frag maps (32x32x16): A/B lane holds row/col = lane&31, k = (lane>>5)*8+j.
// C/D: col = lane&31, row = (reg&3)+8*(reg>>2)+4*(lane>>5)  [m74/m101].
// Output: bx < nf32 -> f32 at col bx*128 (ldc32); else f16 at (bx-nf32)*128.
// Row-major XCD swizzle: lsw=(bid&7)*(nbx*8)+(bid>>3); by=lsw/nbx; bx=lsw%nbx.
// K % 64 == 0. M = 8192 (64 by-tiles).
__global__ __launch_bounds__(256, 4)
void gemm128(const u16* __restrict__ A, const u16* __restrict__ Bt,
             float* __restrict__ Cf32, u16* __restrict__ Cf16,
             int K, int ldc32, int ldc16, int nbx, int nf32) {
  __shared__ __align__(16) u16 As0[128 * 32];
  __shared__ __align__(16) u16 As1[128 * 32];
  __shared__ __align__(16) u16 Bs0[128 * 32];
  __shared__ __align__(16) u16 Bs1[128 * 32];
  const int tid  = threadIdx.x;
  const int lane = tid & 63;
  const int wave = tid >> 6;          // 0..3
  const int wm = (wave & 1) * 64;
  const int wn = (wave >> 1) * 64;
  const int bid = blockIdx.x;
  const int lsw = (bid & 7) * (nbx << 3) + (bid >> 3);
  const int by  = lsw / nbx;
  const int bx  = lsw - by * nbx;
  const size_t bm = (size_t)by * 128;
  const u16* Ab = A  + bm * (size_t)K;
  const u16* Bb = Bt + (size_t)bx * 128 * K;

  // staging: 512 granules of 16B per operand; thread covers g=tid and g=tid+256.
  // row = g>>2 (r0, r0+64), dest slot = tid&3, source col pre-swizzled
  // (mask (row>>1)&3 is identical for row and row+64).
  const int r0   = tid >> 2;                                  // 0..63
  const int scol = (((tid & 3) ^ ((r0 >> 1) & 3)) << 3);      // element col

  // fragment read coords
  const int l31 = lane & 31;
  const int kh  = lane >> 5;                                  // 0/1
  const int fsw = (l31 >> 1) & 3;                             // row swizzle mask

  f32x16 acc[2][2];
#pragma unroll
  for (int i = 0; i < 2; i++)
#pragma unroll
    for (int j = 0; j < 2; j++)
#pragma unroll
      for (int r = 0; r < 16; r++) acc[i][j][r] = 0.f;

#define STAGE(AS, BS, kk)                                                      \
  do {                                                                         \
    gload16(Ab + (size_t)r0 * K + (kk) + scol, &AS[tid * 8]);                  \
    gload16(Ab + (size_t)(64 + r0) * K + (kk) + scol, &AS[(tid + 256) * 8]);   \
    gload16(Bb + (size_t)r0 * K + (kk) + scol, &BS[tid * 8]);                  \
    gload16(Bb + (size_t)(64 + r0) * K + (kk) + scol, &BS[(tid + 256) * 8]);   \
  } while (0)

#define COMPUTE(AS, BS)                                                        \
  do {                                                                         \
    f16x8 av[2], bv[2];                                                        \
    _Pragma("unroll")                                                          \
    for (int ks = 0; ks < 2; ks++) {                                           \
      const int slot = ((ks * 2 + kh) ^ fsw) << 3;                             \
      _Pragma("unroll")                                                        \
      for (int ai = 0; ai < 2; ai++)                                           \
        av[ai] = *(const f16x8*)&AS[(wm + ai * 32 + l31) * 32 + slot];         \
      _Pragma("unroll")                                                        \
      for (int bj = 0; bj < 2; bj++)                                           \
        bv[bj] = *(const f16x8*)&BS[(wn + bj * 32 + l31) * 32 + slot];         \
      __builtin_amdgcn_s_setprio(1);                                           \
      _Pragma("unroll")                                                        \
      for (int ai = 0; ai < 2; ai++)                                           \
        _Pragma("unroll")                                                      \
        for (int bj = 0; bj < 2; bj++)                                         \
          acc[ai][bj] = __builtin_amdgcn_mfma_f32_32x32x16_f16(                \
              av[ai], bv[bj], acc[ai][bj], 0, 0, 0);                           \
      __builtin_amdgcn_s_setprio(0);                                           \
    }                                                                          \
  } while (0)

  STAGE(As0, Bs0, 0);                // 4 in flight
  STAGE(As1, Bs1, 32);               // 8 in flight
  WAITV4();                          // buf0's 4 landed (own wave)
  BAR();                             // all waves' buf0 landed
  for (int k0 = 0; k0 < K; k0 += 64) {
    COMPUTE(As0, Bs0);
    BAR();                           // all waves done reading buf0
    if (k0 + 64 < K) { STAGE(As0, Bs0, k0 + 64); WAITV4(); }
    else             { WAITV0(); }
    BAR();                           // buf1 ready
    COMPUTE(As1, Bs1);
    BAR();                           // all waves done reading buf1
    if (k0 + 96 < K) { STAGE(As1, Bs1, k0 + 96); WAITV4(); }
    BAR();                           // buf0 (next) ready
  }
#undef STAGE
#undef COMPUTE

  // C/D (32x32): col = lane&31, row = (reg&3) + 8*(reg>>2) + 4*kh  [m74/m101]
  if (bx < nf32) {
    const size_t cb = (size_t)bx * 128;
#pragma unroll
    for (int ai = 0; ai < 2; ai++)
#pragma unroll
      for (int bj = 0; bj < 2; bj++)
#pragma unroll
        for (int r = 0; r < 16; r++) {
          size_t row = bm + wm + ai * 32 + (r & 3) + 8 * (r >> 2) + 4 * kh;
          size_t col = cb + wn + bj * 32 + l31;
          Cf32[row * ldc32 + col] = acc[ai][bj][r];
        }
  } else {
    const size_t cb = (size_t)(bx - nf32) * 128;
#pragma unroll
    for (int ai = 0; ai < 2; ai++)
#pragma unroll
      for (int bj = 0; bj < 2; bj++)
#pragma unroll
        for (int r = 0; r < 16; r++) {
          size_t row = bm + wm + ai * 32 + (r & 3) + 8 * (r >> 2) + 4 * kh;
          size_t col = cb + wn + bj * 32 + l31;
          Cf16[row * ldc16 + col] = f2h(acc[ai][bj][r]);
        }
  }
}

// ---------------- chunked SSM scan ----------------
// xzx: [M][NXPAD] f32 (x 0..4095 | B 4096..4127 | C 4128..4159 | pad). xzz: [M][4096] fp16.
__global__ __launch_bounds__(64)
void scan_pass1(const float* __restrict__ xzx, const float* __restrict__ conv_w,
                const float* __restrict__ A_log, const float* __restrict__ dt_bias,
                float* __restrict__ E) {
  const int bid = blockIdx.x;
  const int c   = bid & (NCHUNK - 1);
  const int bg  = bid >> 6;
  const int g   = bg & (GHEADS - 1);
  const int b   = bg >> 5;
  const int lane = threadIdx.x;
  const int ch0 = g * DH + lane, ch1 = ch0 + 64;

  const f32x4 w0 = ((const f32x4*)conv_w)[ch0];
  const f32x4 w1 = ((const f32x4*)conv_w)[ch1];
  const float dt = log1pf(expf(dt_bias[g]));
  const float Ac = -expf(A_log[g]);
  const float dA = expf(dt * Ac);

  const int l0 = c * SCHUNK;
  const float* base = xzx + (size_t)b * LSEQ * NXPAD;

  float xm3 = 0, xm2 = 0, xm1 = 0, Xm3 = 0, Xm2 = 0, Xm1 = 0;
#pragma unroll
  for (int j = 0; j < 3; j++) {
    int l = l0 - 3 + j;
    float v0 = 0, v1 = 0;
    if (l >= 0) {
      const float* rp = base + (size_t)l * NXPAD;
      v0 = rp[ch0]; v1 = rp[ch1];
    }
    if (j == 0) { xm3 = v0; Xm3 = v1; }
    else if (j == 1) { xm2 = v0; Xm2 = v1; }
    else { xm1 = v0; Xm1 = v1; }
  }
  float h0 = 0.f, h1 = 0.f;
  for (int t = 0; t < SCHUNK; t++) {
    const float* rp = base + (size_t)(l0 + t) * NXPAD;
    float xc0 = rp[ch0], xc1 = rp[ch1];
    float cx0 = w0[0] * xm3 + w0[1] * xm2 + w0[2] * xm1 + w0[3] * xc0;
    float cx1 = w1[0] * Xm3 + w1[1] * Xm2 + w1[2] * Xm1 + w1[3] * xc1;
    xm3 = xm2; xm2 = xm1; xm1 = xc0;
    Xm3 = Xm2; Xm2 = Xm1; Xm1 = xc1;
    float u = dt * rp[DGATE + g];
    h0 = dA * h0 + u * silu(cx0);
    h1 = dA * h1 + u * silu(cx1);
  }
  float* ep = E + (size_t)bid * DH;
  ep[lane] = h0; ep[lane + 64] = h1;
}

__global__ __launch_bounds__(64)
void scan_pass2(const float* __restrict__ E, float* __restrict__ Hs,
                const float* __restrict__ A_log, const float* __restrict__ dt_bias) {
  const int bg = blockIdx.x;
  const int g = bg & (GHEADS - 1);
  const int lane = threadIdx.x;
  const float dt = log1pf(expf(dt_bias[g]));
  const float Ac = -expf(A_log[g]);
  const float dAS = expf(dt * Ac * (float)SCHUNK);
  float h0 = 0.f, h1 = 0.f;
  for (int c = 0; c < NCHUNK; c++) {
    size_t idx = ((size_t)bg * NCHUNK + c) * DH;
    Hs[idx + lane] = h0; Hs[idx + lane + 64] = h1;
    h0 = dAS * h0 + E[idx + lane];
    h1 = dAS * h1 + E[idx + lane + 64];
  }
}

__global__ __launch_bounds__(64)
void scan_pass3(const float* __restrict__ xzx, const u16* __restrict__ xzz,
                const float* __restrict__ conv_w,
                const float* __restrict__ A_log, const float* __restrict__ dt_bias,
                const float* __restrict__ norm_w, const float* __restrict__ Hs,
                u16* __restrict__ gbuf) {
  const int bid = blockIdx.x;
  const int c   = bid & (NCHUNK - 1);
  const int bg  = bid >> 6;
  const int g   = bg & (GHEADS - 1);
  const int b   = bg >> 5;
  const int lane = threadIdx.x;
  const int ch0 = g * DH + lane, ch1 = ch0 + 64;

  const f32x4 wx0 = ((const f32x4*)conv_w)[ch0];
  const f32x4 wx1 = ((const f32x4*)conv_w)[ch1];
  const f32x4 wz0 = ((const f32x4*)conv_w)[DGATE + ch0];
  const f32x4 wz1 = ((const f32x4*)conv_w)[DGATE + ch1];
  const float nw0 = norm_w[lane], nw1 = norm_w[lane + 64];

  const float dt = log1pf(expf(dt_bias[g]));
  const float Ac = -expf(A_log[g]);
  const float dA = expf(dt * Ac);

  const int l0 = c * SCHUNK;
  const float* basex = xzx + (size_t)b * LSEQ * NXPAD;
  const u16*   basez = xzz + (size_t)b * LSEQ * DGATE;

  float xm3 = 0, xm2 = 0, xm1 = 0, Xm3 = 0, Xm2 = 0, Xm1 = 0;
  float zm3 = 0, zm2 = 0, zm1 = 0, Zm3 = 0, Zm2 = 0, Zm1 = 0;
#pragma unroll
  for (int j = 0; j < 3; j++) {
    int l = l0 - 3 + j;
    float vx0 = 0, vx1 = 0, vz0 = 0, vz1 = 0;
    if (l >= 0) {
      const float* rp = basex + (size_t)l * NXPAD;
      const u16*   rz = basez + (size_t)l * DGATE;
      vx0 = rp[ch0]; vx1 = rp[ch1];
      vz0 = h2f(rz[ch0]); vz1 = h2f(rz[ch1]);
    }
    if (j == 0) { xm3 = vx0; Xm3 = vx1; zm3 = vz0; Zm3 = vz1; }
    else if (j == 1) { xm2 = vx0; Xm2 = vx1; zm2 = vz0; Zm2 = vz1; }
    else { xm1 = vx0; Xm1 = vx1; zm1 = vz0; Zm1 = vz1; }
  }
  float h0 = Hs[(size_t)bid * DH + lane];
  float h1 = Hs[(size_t)bid * DH + lane + 64];
  for (int t = 0; t < SCHUNK; t++) {
    const int l = l0 + t;
    const float* rp = basex + (size_t)l * NXPAD;
    const u16*   rz = basez + (size_t)l * DGATE;
    float xc0 = rp[ch0], xc1 = rp[ch1];
    float zc0 = h2f(rz[ch0]), zc1 = h2f(rz[ch1]);
    float cx0 = wx0[0] * xm3 + wx0[1] * xm2 + wx0[2] * xm1 + wx0[3] * xc0;
    float cx1 = wx1[0] * Xm3 + wx1[1] * Xm2 + wx1[2] * Xm1 + wx1[3] * xc1;
    float cz0 = wz0[0] * zm3 + wz0[1] * zm2 + wz0[2] * zm1 + wz0[3] * zc0;
    float cz1 = wz1[0] * Zm3 + wz1[1] * Zm2 + wz1[2] * Zm1 + wz1[3] * zc1;
    xm3 = xm2; xm2 = xm1; xm1 = xc0;  Xm3 = Xm2; Xm2 = Xm1; Xm1 = xc1;
    zm3 = zm2; zm2 = zm1; zm1 = zc0;  Zm3 = Zm2; Zm2 = Zm1; Zm1 = zc1;
    float bcl = rp[DGATE + g];
    float ccl = rp[DGATE + 32 + g];
    float u = dt * bcl;
    h0 = dA * h0 + u * silu(cx0);
    h1 = dA * h1 + u * silu(cx1);
    float y0 = ccl * h0, y1 = ccl * h1;
    float ss = y0 * y0 + y1 * y1;
    ss += __shfl_xor(ss, 32); ss += __shfl_xor(ss, 16); ss += __shfl_xor(ss, 8);
    ss += __shfl_xor(ss, 4);  ss += __shfl_xor(ss, 2);  ss += __shfl_xor(ss, 1);
    const float sc = rsqrtf(ss * (1.0f / DH) + 1e-6f);
    u16* op = gbuf + (size_t)(b * LSEQ + l) * DGATE + g * DH;
    op[lane]      = f2h(y0 * sc * nw0 * silu(cz0));
    op[lane + 64] = f2h(y1 * sc * nw1 * silu(cz1));
  }
}

// ---------------- launch ----------------
extern "C" void kernel_launch(void* const* d_in, const int* in_sizes, int n_in,
                              void* d_out, int out_size, void* d_ws, size_t ws_size,
                              hipStream_t stream) {
  (void)in_sizes; (void)n_in; (void)out_size; (void)ws_size;
  const float* hs    = (const float*)d_in[0];
  const float* Wqkv  = (const float*)d_in[1];
  const float* Wb    = (const float*)d_in[2];
  const float* Wa    = (const float*)d_in[3];
  const float* convw = (const float*)d_in[4];
  const float* Wout  = (const float*)d_in[5];
  const float* normw = (const float*)d_in[6];
  const float* Alog  = (const float*)d_in[7];
  const float* dtb   = (const float*)d_in[8];
  float* out = (float*)d_out;

  // ws layout (~302 MB; <= 313 proven-safe):
  // [xzx 142.6 | xzz 67.1 | wcomb 43.3 | pad 24 | wout 21.0 | E 2.1 | Hst 2.1]
  char* ws = (char*)d_ws;
  size_t off = 0;
  auto alloc = [&](size_t bytes) { void* p = ws + off; off += (bytes + 255) & ~(size_t)255; return p; };
  float* xzx    = (float*)alloc((size_t)MROWS * NXPAD * 4);      // 142.6 MB
  u16*   xzz    = (u16*)alloc((size_t)MROWS * DGATE * 2);        // 67.1 MB
  u16*   wcomb  = (u16*)alloc((size_t)NWCOMB * H_DIM * 2);       // 43.3 MB
  (void)alloc((size_t)24 << 20);                                 // 24 MB pad (gbuf tail)
  u16*   wout_h = (u16*)alloc((size_t)H_DIM * DGATE * 2);        // 21.0 MB
  float* E      = (float*)alloc((size_t)BSZ * GHEADS * NCHUNK * DH * 4);
  float* Hst    = (float*)alloc((size_t)BSZ * GHEADS * NCHUNK * DH * 4);
  // gbuf (67.1 MB) aliases [wcomb|pad] (67.3 MB): wcomb dead after GEMM1;
  // pass3 (writer) launches strictly after it. Never touches wout.
  u16*   gbuf   = wcomb;
  // hs_h (fp16, 41.9 MB) lives in d_out (83.9 MB), dead until GEMM2 overwrites it.
  u16*   hs_h   = (u16*)d_out;

  const int n4_hs = MROWS * H_DIM / 4;
  cast_f32_f16<<<(n4_hs + 255) / 256, 256, 0, stream>>>(hs, hs_h, n4_hs);
  build_wc<<<NWCOMB, 256, 0, stream>>>(Wqkv, Wb, Wa, wcomb);
  const int n4_wo = H_DIM * DGATE / 4;
  cast_f32_f16<<<(n4_wo + 255) / 256, 256, 0, stream>>>(Wout, wout_h, n4_wo);

  // Fused GEMM1: [x|B|C -> f32 xzx] + [z -> f16 xzz].  grid 66*64 = 4224
  gemm128<<<66 * 64, 256, 0, stream>>>(hs_h, wcomb, xzx, xzz, H_DIM, NXPAD, DGATE, 66, 34);

  scan_pass1<<<BSZ * GHEADS * NCHUNK, 64, 0, stream>>>(xzx, convw, Alog, dtb, E);
  scan_pass2<<<BSZ * GHEADS, 64, 0, stream>>>(E, Hst, Alog, dtb);
  scan_pass3<<<BSZ * GHEADS * NCHUNK, 64, 0, stream>>>(xzx, xzz, convw, Alog, dtb, normw, Hst, gbuf);

  // GEMM2: out = gated @ W_out^T -> f32 [8192, 2560].  grid 20*64 = 1280
  gemm128<<<20 * 64, 256, 0, stream>>>(gbuf, wout_h, out, nullptr, DGATE, H_DIM, 0, 20, 20);
}